// Round 1
// baseline (6776.960 us; speedup 1.0000x reference)
//
#include <hip/hip_runtime.h>
#include <cstdint>
#include <cstddef>
#include <math.h>

#define T_TOK 2048
#define DMODEL 1280
#define NHEAD 16
#define HDIM 80
#define HALFD 40
#define FFDIM 3420
#define DEPTH_L 4
#define OUTD 3584
#define PATCH_INDIM 1176
#define WIN 64
#define NWIN (T_TOK / WIN)
#define EPSV 1e-6f
#define SCALE_ATTN 0.11180339887498949f  // 1/sqrt(80)

// ---------------------------------------------------------------------------
// Tiled fp32 GEMM: C[M,N] = A[M,K] @ B[K,N] (+ bias[N]) (+ res[M,N])
// 64x64 tile, BK=16, 256 threads, 4x4 microtile per thread.
// Requires K % 4 == 0 and N % 4 == 0 (true for all shapes here).
// ---------------------------------------------------------------------------
__global__ __launch_bounds__(256) void gemm_kernel(
    const float* __restrict__ A, const float* __restrict__ B,
    const float* __restrict__ bias, const float* res,
    float* C, int M, int N, int K)
{
    __shared__ __align__(16) float As[16][68];  // [k][m], stride 68 kills conflicts
    __shared__ __align__(16) float Bs[16][64];  // [k][n]

    const int tid = threadIdx.x;
    const int bx = blockIdx.x, by = blockIdx.y;
    const int tx = tid & 15, ty = tid >> 4;
    const int row0 = by * 64, col0 = bx * 64;

    float acc[4][4] = {};

    const int la_m = tid >> 2;        // 0..63
    const int la_k = (tid & 3) * 4;   // 0,4,8,12
    const int lb_k = tid >> 4;        // 0..15
    const int lb_n = (tid & 15) * 4;  // 0..60

    for (int kk = 0; kk < K; kk += 16) {
        // A tile -> As[k][m] (transposed store)
        {
            const int m = row0 + la_m;
            const int k = kk + la_k;
            if (m < M && k < K) {
                const float4 a4 = *(const float4*)(A + (size_t)m * K + k);
                As[la_k + 0][la_m] = a4.x;
                As[la_k + 1][la_m] = a4.y;
                As[la_k + 2][la_m] = a4.z;
                As[la_k + 3][la_m] = a4.w;
            } else {
                As[la_k + 0][la_m] = 0.f;
                As[la_k + 1][la_m] = 0.f;
                As[la_k + 2][la_m] = 0.f;
                As[la_k + 3][la_m] = 0.f;
            }
        }
        // B tile -> Bs[k][n]
        {
            const int k = kk + lb_k;
            const int n = col0 + lb_n;
            if (k < K && n < N) {
                *(float4*)&Bs[lb_k][lb_n] = *(const float4*)(B + (size_t)k * N + n);
            } else {
                Bs[lb_k][lb_n + 0] = 0.f;
                Bs[lb_k][lb_n + 1] = 0.f;
                Bs[lb_k][lb_n + 2] = 0.f;
                Bs[lb_k][lb_n + 3] = 0.f;
            }
        }
        __syncthreads();

        #pragma unroll
        for (int k = 0; k < 16; k++) {
            const float4 a = *(const float4*)&As[k][ty * 4];
            const float4 b = *(const float4*)&Bs[k][tx * 4];
            const float av[4] = {a.x, a.y, a.z, a.w};
            const float bv[4] = {b.x, b.y, b.z, b.w};
            #pragma unroll
            for (int i = 0; i < 4; i++)
                #pragma unroll
                for (int j = 0; j < 4; j++)
                    acc[i][j] += av[i] * bv[j];
        }
        __syncthreads();
    }

    #pragma unroll
    for (int i = 0; i < 4; i++) {
        const int m = row0 + ty * 4 + i;
        if (m >= M) continue;
        #pragma unroll
        for (int j = 0; j < 4; j++) {
            const int n = col0 + tx * 4 + j;
            if (n >= N) continue;
            float v = acc[i][j];
            if (bias) v += bias[n];
            if (res) v += res[(size_t)m * N + n];
            C[(size_t)m * N + n] = v;
        }
    }
}

// ---------------------------------------------------------------------------
// RMSNorm: one block per row. out[row] = x[row] * scale * rsqrt(mean(x^2)+eps)
// ---------------------------------------------------------------------------
__global__ __launch_bounds__(256) void rmsnorm_kernel(
    const float* __restrict__ x, const float* __restrict__ scale,
    float* __restrict__ out, int D)
{
    const int row = blockIdx.x;
    const float* xr = x + (size_t)row * D;
    float ss = 0.f;
    for (int i = threadIdx.x; i < D; i += 256) { const float v = xr[i]; ss += v * v; }
    for (int off = 32; off > 0; off >>= 1) ss += __shfl_down(ss, off);
    __shared__ float red[4];
    if ((threadIdx.x & 63) == 0) red[threadIdx.x >> 6] = ss;
    __syncthreads();
    const float tot = red[0] + red[1] + red[2] + red[3];
    const float inv = rsqrtf(tot / (float)D + EPSV);
    float* orow = out + (size_t)row * D;
    for (int i = threadIdx.x; i < D; i += 256) orow[i] = xr[i] * scale[i] * inv;
}

// ---------------------------------------------------------------------------
// RoPE applied in-place to q and k inside the qkv buffer (T, 3*D).
// One thread per (t, head, j<HALF).
// ---------------------------------------------------------------------------
__global__ __launch_bounds__(256) void rope_kernel(
    float* __restrict__ qkv, const float* __restrict__ rpe)
{
    const int i = blockIdx.x * 256 + threadIdx.x;
    if (i >= T_TOK * NHEAD * HALFD) return;
    const int t = i / (NHEAD * HALFD);
    const int rem = i - t * (NHEAD * HALFD);
    const int hh = rem / HALFD;
    const int j = rem - hh * HALFD;
    const float ang = rpe[t * HALFD + j];
    const float c = cosf(ang), s = sinf(ang);
    const size_t qb = (size_t)t * (3 * DMODEL) + hh * HDIM + j;
    float r = qkv[qb], im = qkv[qb + HALFD];
    qkv[qb] = r * c - im * s;
    qkv[qb + HALFD] = r * s + im * c;
    const size_t kb = qb + DMODEL;
    r = qkv[kb]; im = qkv[kb + HALFD];
    qkv[kb] = r * c - im * s;
    qkv[kb + HALFD] = r * s + im * c;
}

// ---------------------------------------------------------------------------
// Windowed attention: one block per (window, head). 64 tokens/window.
// q,k staged in LDS; scores->softmax (4 lanes per row, shfl_xor combine);
// v reuses the k buffer after a barrier; o = P @ v.
// ---------------------------------------------------------------------------
__global__ __launch_bounds__(256) void attn_kernel(
    const float* __restrict__ qkv, float* __restrict__ o)
{
    __shared__ float qs[WIN][HDIM + 1];
    __shared__ float ks[WIN][HDIM + 1];   // reused for v
    __shared__ float ps[WIN][WIN];
    const int win = blockIdx.x, hh = blockIdx.y;
    const int t0 = win * WIN;
    const int tid = threadIdx.x;

    for (int i = tid; i < WIN * HDIM; i += 256) {
        const int r = i / HDIM, d = i - r * HDIM;
        const size_t base = (size_t)(t0 + r) * (3 * DMODEL) + hh * HDIM + d;
        qs[r][d] = qkv[base];
        ks[r][d] = qkv[base + DMODEL];
    }
    __syncthreads();

    const int row = tid >> 2, sub = tid & 3;
    float s[16];
    #pragma unroll
    for (int jj = 0; jj < 16; jj++) s[jj] = 0.f;
    for (int d = 0; d < HDIM; d++) {
        const float qv = qs[row][d];
        #pragma unroll
        for (int jj = 0; jj < 16; jj++) s[jj] += qv * ks[sub * 16 + jj][d];
    }
    float mx = -1e30f;
    #pragma unroll
    for (int jj = 0; jj < 16; jj++) { s[jj] *= SCALE_ATTN; mx = fmaxf(mx, s[jj]); }
    for (int off = 1; off < 4; off <<= 1) mx = fmaxf(mx, __shfl_xor(mx, off));
    float l = 0.f;
    #pragma unroll
    for (int jj = 0; jj < 16; jj++) { s[jj] = expf(s[jj] - mx); l += s[jj]; }
    for (int off = 1; off < 4; off <<= 1) l += __shfl_xor(l, off);
    const float inv = 1.f / l;
    #pragma unroll
    for (int jj = 0; jj < 16; jj++) ps[row][sub * 16 + jj] = s[jj] * inv;
    __syncthreads();

    // overwrite ks with v (scores already consumed)
    for (int i = tid; i < WIN * HDIM; i += 256) {
        const int r = i / HDIM, d = i - r * HDIM;
        ks[r][d] = qkv[(size_t)(t0 + r) * (3 * DMODEL) + 2 * DMODEL + hh * HDIM + d];
    }
    __syncthreads();

    for (int i = tid; i < WIN * HDIM; i += 256) {
        const int r = i / HDIM, d = i - r * HDIM;
        float acc = 0.f;
        #pragma unroll
        for (int j = 0; j < WIN; j++) acc += ps[r][j] * ks[j][d];
        o[(size_t)(t0 + r) * DMODEL + hh * HDIM + d] = acc;
    }
}

// ---------------------------------------------------------------------------
// Elementwise: g = silu(g) * u ;  x = gelu_exact(x)
// ---------------------------------------------------------------------------
__global__ __launch_bounds__(256) void silumul_kernel(
    float* __restrict__ g, const float* __restrict__ u, int n)
{
    const int i = blockIdx.x * 256 + threadIdx.x;
    if (i < n) { const float x = g[i]; g[i] = (x / (1.f + expf(-x))) * u[i]; }
}

__global__ __launch_bounds__(256) void gelu_kernel(float* __restrict__ x, int n)
{
    const int i = blockIdx.x * 256 + threadIdx.x;
    if (i < n) { const float v = x[i]; x[i] = 0.5f * v * (1.f + erff(v * 0.70710678118654752f)); }
}

// ---------------------------------------------------------------------------
extern "C" void kernel_launch(void* const* d_in, const int* in_sizes, int n_in,
                              void* d_out, int out_size, void* d_ws, size_t ws_size,
                              hipStream_t stream)
{
    const float* x       = (const float*)d_in[0];
    const float* rpe     = (const float*)d_in[1];
    // d_in[2] = cu_window_seqlens: fixed arange(0,T+1,64) -> hard-coded WIN=64
    const float* patch_w = (const float*)d_in[3];
    const float* qkv_w   = (const float*)d_in[4];
    const float* qkv_b   = (const float*)d_in[5];
    const float* proj_w  = (const float*)d_in[6];
    const float* proj_b  = (const float*)d_in[7];
    const float* norm1_s = (const float*)d_in[8];
    const float* norm2_s = (const float*)d_in[9];
    const float* gate_w  = (const float*)d_in[10];
    const float* gate_b  = (const float*)d_in[11];
    const float* up_w    = (const float*)d_in[12];
    const float* up_b    = (const float*)d_in[13];
    const float* down_w  = (const float*)d_in[14];
    const float* down_b  = (const float*)d_in[15];
    const float* lnq_s   = (const float*)d_in[16];
    const float* fc1_w   = (const float*)d_in[17];
    const float* fc1_b   = (const float*)d_in[18];
    const float* fc2_w   = (const float*)d_in[19];
    const float* fc2_b   = (const float*)d_in[20];
    float* out = (float*)d_out;

    float* ws   = (float*)d_ws;
    float* h    = ws;                                  // 2048*1280
    float* nbuf = h    + (size_t)T_TOK * DMODEL;       // 2048*1280 (also final m: 512x5120 view)
    float* qkv  = nbuf + (size_t)T_TOK * DMODEL;       // 2048*3840
    float* o    = qkv  + (size_t)T_TOK * 3 * DMODEL;   // 2048*1280 (also fc1 out: 512x5120)
    float* g    = o    + (size_t)T_TOK * DMODEL;       // 2048*3420
    float* u    = g    + (size_t)T_TOK * FFDIM;        // 2048*3420

    const dim3 blk(256);
    auto gemm = [&](const float* A, const float* B, const float* bias, const float* res,
                    float* C, int M, int N, int K) {
        dim3 grid((N + 63) / 64, (M + 63) / 64);
        gemm_kernel<<<grid, blk, 0, stream>>>(A, B, bias, res, C, M, N, K);
    };

    // h = x @ patch_w
    gemm(x, patch_w, nullptr, nullptr, h, T_TOK, DMODEL, PATCH_INDIM);

    for (int l = 0; l < DEPTH_L; l++) {
        rmsnorm_kernel<<<T_TOK, blk, 0, stream>>>(h, norm1_s + l * DMODEL, nbuf, DMODEL);
        gemm(nbuf, qkv_w + (size_t)l * DMODEL * 3 * DMODEL, qkv_b + l * 3 * DMODEL,
             nullptr, qkv, T_TOK, 3 * DMODEL, DMODEL);
        rope_kernel<<<(T_TOK * NHEAD * HALFD + 255) / 256, blk, 0, stream>>>(qkv, rpe);
        attn_kernel<<<dim3(NWIN, NHEAD), blk, 0, stream>>>(qkv, o);
        gemm(o, proj_w + (size_t)l * DMODEL * DMODEL, proj_b + l * DMODEL,
             h, h, T_TOK, DMODEL, DMODEL);
        rmsnorm_kernel<<<T_TOK, blk, 0, stream>>>(h, norm2_s + l * DMODEL, nbuf, DMODEL);
        gemm(nbuf, gate_w + (size_t)l * DMODEL * FFDIM, gate_b + l * FFDIM,
             nullptr, g, T_TOK, FFDIM, DMODEL);
        gemm(nbuf, up_w + (size_t)l * DMODEL * FFDIM, up_b + l * FFDIM,
             nullptr, u, T_TOK, FFDIM, DMODEL);
        silumul_kernel<<<(T_TOK * FFDIM + 255) / 256, blk, 0, stream>>>(g, u, T_TOK * FFDIM);
        gemm(g, down_w + (size_t)l * FFDIM * DMODEL, down_b + l * DMODEL,
             h, h, T_TOK, DMODEL, FFDIM);
    }

    // final rmsnorm -> m (contiguous reshape to 512 x 5120)
    rmsnorm_kernel<<<T_TOK, blk, 0, stream>>>(h, lnq_s, nbuf, DMODEL);
    gemm(nbuf, fc1_w, fc1_b, nullptr, o, 512, 5120, 5120);
    gelu_kernel<<<(512 * 5120 + 255) / 256, blk, 0, stream>>>(o, 512 * 5120);
    gemm(o, fc2_w, fc2_b, nullptr, out, 512, OUTD, 5120);
}

// Round 2
// 2367.322 us; speedup vs baseline: 2.8627x; 2.8627x over previous
//
#include <hip/hip_runtime.h>
#include <hip/hip_bf16.h>
#include <cstdint>
#include <cstddef>
#include <math.h>

#define T_TOK 2048
#define DMODEL 1280
#define NHEAD 16
#define HDIM 80
#define HALFD 40
#define FFDIM 3420
#define FF_PAD 3456        /* 27*128, N-pad for gate/up GEMM C */
#define FFK_PAD 3424       /* 107*32, K-pad for down GEMM A    */
#define PATCH_INDIM 1176
#define PATCHK_PAD 1184    /* 37*32 */
#define DEPTH_L 4
#define OUTD 3584
#define WIN 64
#define NWIN (T_TOK / WIN)
#define MERGED 5120
#define EPSV 1e-6f
#define SCALE_ATTN 0.11180339887498949f

typedef __attribute__((ext_vector_type(8))) short short8;
typedef __attribute__((ext_vector_type(4))) float f32x4;
typedef unsigned short ushort_t;

// ---------------------------------------------------------------------------
// bf16 MFMA GEMM (m97 structure): C[M,Nc]fp32 = A[M,Kp]bf16 @ Bt[N,Kp]bf16^T
// BM=BN=128, BK=32, 256 thr = 4 waves, each wave 64x64 via 4x4 16x16x32 MFMAs.
// Requires M%128==0, Nc%128==0, Kp%32==0. Epilogue guarded by col<Nreal.
// ---------------------------------------------------------------------------
__global__ __launch_bounds__(256) void gemm_bf16(
    const ushort_t* __restrict__ A, const ushort_t* __restrict__ Bt,
    const float* __restrict__ bias, const float* __restrict__ res,
    float* __restrict__ C, int M, int Nreal, int Nc, int Kp)
{
    __shared__ ushort_t As[128 * 32];
    __shared__ ushort_t Bs[128 * 32];

    const int tid  = threadIdx.x;
    const int lane = tid & 63;
    const int wave = tid >> 6;
    const int row0 = blockIdx.y * 128;
    const int col0 = blockIdx.x * 128;
    const int wm0  = (wave & 1) * 64;
    const int wn0  = (wave >> 1) * 64;

    f32x4 acc[4][4] = {};

    const int ldr = tid >> 2;        // 0..63   staging row within tile
    const int ldc = (tid & 3) * 8;   // 0,8,16,24  bf16 col offset (16B chunk)

    const int mrow  = lane & 15;
    const int khalf = (lane >> 4) * 8;

    for (int kk = 0; kk < Kp; kk += 32) {
        const ushort_t* ga = A  + (size_t)(row0 + ldr) * Kp + kk + ldc;
        const ushort_t* gb = Bt + (size_t)(col0 + ldr) * Kp + kk + ldc;
        __builtin_amdgcn_global_load_lds(
            (const __attribute__((address_space(1))) void*)ga,
            (__attribute__((address_space(3))) void*)(As + tid * 8), 16, 0, 0);
        __builtin_amdgcn_global_load_lds(
            (const __attribute__((address_space(1))) void*)(ga + (size_t)64 * Kp),
            (__attribute__((address_space(3))) void*)(As + 2048 + tid * 8), 16, 0, 0);
        __builtin_amdgcn_global_load_lds(
            (const __attribute__((address_space(1))) void*)gb,
            (__attribute__((address_space(3))) void*)(Bs + tid * 8), 16, 0, 0);
        __builtin_amdgcn_global_load_lds(
            (const __attribute__((address_space(1))) void*)(gb + (size_t)64 * Kp),
            (__attribute__((address_space(3))) void*)(Bs + 2048 + tid * 8), 16, 0, 0);
        __syncthreads();

        short8 af[4], bf[4];
        #pragma unroll
        for (int i = 0; i < 4; i++) {
            af[i] = *(const short8*)&As[(wm0 + i * 16 + mrow) * 32 + khalf];
            bf[i] = *(const short8*)&Bs[(wn0 + i * 16 + mrow) * 32 + khalf];
        }
        #pragma unroll
        for (int i = 0; i < 4; i++)
            #pragma unroll
            for (int j = 0; j < 4; j++)
                acc[i][j] = __builtin_amdgcn_mfma_f32_16x16x32_bf16(
                    af[i], bf[j], acc[i][j], 0, 0, 0);
        __syncthreads();
    }

    const int crow0 = row0 + wm0 + (lane >> 4) * 4;
    const int ccol0 = col0 + wn0 + (lane & 15);
    #pragma unroll
    for (int j = 0; j < 4; j++) {
        const int col = ccol0 + j * 16;
        if (col >= Nreal) continue;
        const float bv = bias ? bias[col] : 0.f;
        #pragma unroll
        for (int i = 0; i < 4; i++) {
            #pragma unroll
            for (int r = 0; r < 4; r++) {
                const int row = crow0 + i * 16 + r;
                float v = acc[i][j][r] + bv;
                if (res) v += res[(size_t)row * Nc + col];
                C[(size_t)row * Nc + col] = v;
            }
        }
    }
}

// ---------------------------------------------------------------------------
// Tiled transpose + fp32->bf16: in[K,N] fp32 -> out[Np,Kp] bf16 (zero-padded)
// ---------------------------------------------------------------------------
__global__ __launch_bounds__(256) void transpose_cvt(
    const float* __restrict__ in, __hip_bfloat16* __restrict__ out,
    int K, int N, int Kp, int Np)
{
    __shared__ float t[32][33];
    const int k0 = blockIdx.x * 32, n0 = blockIdx.y * 32;
    const int tx = threadIdx.x & 31, ty = threadIdx.x >> 5;  // 32x8
    #pragma unroll
    for (int i = 0; i < 4; i++) {
        const int k = k0 + ty + i * 8, n = n0 + tx;
        t[ty + i * 8][tx] = (k < K && n < N) ? in[(size_t)k * N + n] : 0.f;
    }
    __syncthreads();
    #pragma unroll
    for (int i = 0; i < 4; i++) {
        const int n = n0 + ty + i * 8, k = k0 + tx;
        if (n < Np && k < Kp)
            out[(size_t)n * Kp + k] = __float2bfloat16(t[tx][ty + i * 8]);
    }
}

// fp32 [M,K] -> bf16 [M,Kp] with zero pad (row-major, no transpose)
__global__ __launch_bounds__(256) void cvt_pad(
    const float* __restrict__ in, __hip_bfloat16* __restrict__ out,
    int M, int K, int Kp)
{
    const int i = blockIdx.x * 256 + threadIdx.x;
    if (i >= M * Kp) return;
    const int m = i / Kp, k = i - m * Kp;
    out[i] = __float2bfloat16(k < K ? in[(size_t)m * K + k] : 0.f);
}

// ---------------------------------------------------------------------------
// RMSNorm fp32 in -> bf16 out. One block per row.
// ---------------------------------------------------------------------------
__global__ __launch_bounds__(256) void rmsnorm_kernel(
    const float* __restrict__ x, const float* __restrict__ scale,
    __hip_bfloat16* __restrict__ out, int D)
{
    const int row = blockIdx.x;
    const float* xr = x + (size_t)row * D;
    float ss = 0.f;
    for (int i = threadIdx.x; i < D; i += 256) { const float v = xr[i]; ss += v * v; }
    for (int off = 32; off > 0; off >>= 1) ss += __shfl_down(ss, off);
    __shared__ float red[4];
    if ((threadIdx.x & 63) == 0) red[threadIdx.x >> 6] = ss;
    __syncthreads();
    const float tot = red[0] + red[1] + red[2] + red[3];
    const float inv = rsqrtf(tot / (float)D + EPSV);
    __hip_bfloat16* orow = out + (size_t)row * D;
    for (int i = threadIdx.x; i < D; i += 256)
        orow[i] = __float2bfloat16(xr[i] * scale[i] * inv);
}

// ---------------------------------------------------------------------------
// RoPE in-place on fp32 qkv (T, 3*D)
// ---------------------------------------------------------------------------
__global__ __launch_bounds__(256) void rope_kernel(
    float* __restrict__ qkv, const float* __restrict__ rpe)
{
    const int i = blockIdx.x * 256 + threadIdx.x;
    if (i >= T_TOK * NHEAD * HALFD) return;
    const int t = i / (NHEAD * HALFD);
    const int rem = i - t * (NHEAD * HALFD);
    const int hh = rem / HALFD;
    const int j = rem - hh * HALFD;
    const float ang = rpe[t * HALFD + j];
    const float c = cosf(ang), s = sinf(ang);
    const size_t qb = (size_t)t * (3 * DMODEL) + hh * HDIM + j;
    float r = qkv[qb], im = qkv[qb + HALFD];
    qkv[qb] = r * c - im * s;
    qkv[qb + HALFD] = r * s + im * c;
    const size_t kb = qb + DMODEL;
    r = qkv[kb]; im = qkv[kb + HALFD];
    qkv[kb] = r * c - im * s;
    qkv[kb + HALFD] = r * s + im * c;
}

// ---------------------------------------------------------------------------
// Windowed attention (fp32 math), writes bf16 o. One block per (window, head).
// ---------------------------------------------------------------------------
__global__ __launch_bounds__(256) void attn_kernel(
    const float* __restrict__ qkv, __hip_bfloat16* __restrict__ o)
{
    __shared__ float qs[WIN][HDIM + 1];
    __shared__ float ks[WIN][HDIM + 1];   // reused for v
    __shared__ float ps[WIN][WIN];
    const int win = blockIdx.x, hh = blockIdx.y;
    const int t0 = win * WIN;
    const int tid = threadIdx.x;

    for (int i = tid; i < WIN * HDIM; i += 256) {
        const int r = i / HDIM, d = i - r * HDIM;
        const size_t base = (size_t)(t0 + r) * (3 * DMODEL) + hh * HDIM + d;
        qs[r][d] = qkv[base];
        ks[r][d] = qkv[base + DMODEL];
    }
    __syncthreads();

    const int row = tid >> 2, sub = tid & 3;
    float s[16];
    #pragma unroll
    for (int jj = 0; jj < 16; jj++) s[jj] = 0.f;
    for (int d = 0; d < HDIM; d++) {
        const float qv = qs[row][d];
        #pragma unroll
        for (int jj = 0; jj < 16; jj++) s[jj] += qv * ks[sub * 16 + jj][d];
    }
    float mx = -1e30f;
    #pragma unroll
    for (int jj = 0; jj < 16; jj++) { s[jj] *= SCALE_ATTN; mx = fmaxf(mx, s[jj]); }
    for (int off = 1; off < 4; off <<= 1) mx = fmaxf(mx, __shfl_xor(mx, off));
    float l = 0.f;
    #pragma unroll
    for (int jj = 0; jj < 16; jj++) { s[jj] = expf(s[jj] - mx); l += s[jj]; }
    for (int off = 1; off < 4; off <<= 1) l += __shfl_xor(l, off);
    const float inv = 1.f / l;
    #pragma unroll
    for (int jj = 0; jj < 16; jj++) ps[row][sub * 16 + jj] = s[jj] * inv;
    __syncthreads();

    for (int i = tid; i < WIN * HDIM; i += 256) {
        const int r = i / HDIM, d = i - r * HDIM;
        ks[r][d] = qkv[(size_t)(t0 + r) * (3 * DMODEL) + 2 * DMODEL + hh * HDIM + d];
    }
    __syncthreads();

    for (int i = tid; i < WIN * HDIM; i += 256) {
        const int r = i / HDIM, d = i - r * HDIM;
        float acc = 0.f;
        #pragma unroll
        for (int j = 0; j < WIN; j++) acc += ps[r][j] * ks[j][d];
        o[(size_t)(t0 + r) * DMODEL + hh * HDIM + d] = __float2bfloat16(acc);
    }
}

// ---------------------------------------------------------------------------
// silu(g)*u: g,u fp32 [T, FF_PAD] (cols<FFDIM valid) -> bf16 [T, FFK_PAD]
// ---------------------------------------------------------------------------
__global__ __launch_bounds__(256) void silumul_kernel(
    const float* __restrict__ g, const float* __restrict__ u,
    __hip_bfloat16* __restrict__ out)
{
    const int i = blockIdx.x * 256 + threadIdx.x;
    if (i >= T_TOK * FFK_PAD) return;
    const int row = i / FFK_PAD, k = i - row * FFK_PAD;
    float v = 0.f;
    if (k < FFDIM) {
        const float x = g[(size_t)row * FF_PAD + k];
        v = (x / (1.f + expf(-x))) * u[(size_t)row * FF_PAD + k];
    }
    out[i] = __float2bfloat16(v);
}

// gelu exact on fp32 [n] -> bf16 [n]
__global__ __launch_bounds__(256) void gelu_kernel(
    const float* __restrict__ x, __hip_bfloat16* __restrict__ out, int n)
{
    const int i = blockIdx.x * 256 + threadIdx.x;
    if (i < n) {
        const float v = x[i];
        out[i] = __float2bfloat16(0.5f * v * (1.f + erff(v * 0.70710678118654752f)));
    }
}

// ---------------------------------------------------------------------------
extern "C" void kernel_launch(void* const* d_in, const int* in_sizes, int n_in,
                              void* d_out, int out_size, void* d_ws, size_t ws_size,
                              hipStream_t stream)
{
    const float* x       = (const float*)d_in[0];
    const float* rpe     = (const float*)d_in[1];
    const float* patch_w = (const float*)d_in[3];
    const float* qkv_w   = (const float*)d_in[4];
    const float* qkv_b   = (const float*)d_in[5];
    const float* proj_w  = (const float*)d_in[6];
    const float* proj_b  = (const float*)d_in[7];
    const float* norm1_s = (const float*)d_in[8];
    const float* norm2_s = (const float*)d_in[9];
    const float* gate_w  = (const float*)d_in[10];
    const float* gate_b  = (const float*)d_in[11];
    const float* up_w    = (const float*)d_in[12];
    const float* up_b    = (const float*)d_in[13];
    const float* down_w  = (const float*)d_in[14];
    const float* down_b  = (const float*)d_in[15];
    const float* lnq_s   = (const float*)d_in[16];
    const float* fc1_w   = (const float*)d_in[17];
    const float* fc1_b   = (const float*)d_in[18];
    const float* fc2_w   = (const float*)d_in[19];
    const float* fc2_b   = (const float*)d_in[20];
    float* out = (float*)d_out;

    char* p = (char*)d_ws;
    auto alloc = [&](size_t bytes) -> void* {
        void* r = (void*)p; p += (bytes + 255) & ~(size_t)255; return r;
    };
    // fp32 buffers
    float* h    = (float*)alloc((size_t)T_TOK * DMODEL * 4);
    float* qkvf = (float*)alloc((size_t)T_TOK * 3 * DMODEL * 4);
    float* gf   = (float*)alloc((size_t)T_TOK * FF_PAD * 4);
    float* uf   = (float*)alloc((size_t)T_TOK * FF_PAD * 4);
    float* fc1f = (float*)alloc((size_t)512 * MERGED * 4);
    // bf16 buffers
    __hip_bfloat16* x_b    = (__hip_bfloat16*)alloc((size_t)T_TOK * PATCHK_PAD * 2);
    __hip_bfloat16* n_b    = (__hip_bfloat16*)alloc((size_t)T_TOK * DMODEL * 2);
    __hip_bfloat16* o_b    = (__hip_bfloat16*)alloc((size_t)T_TOK * DMODEL * 2);
    __hip_bfloat16* g_b    = (__hip_bfloat16*)alloc((size_t)T_TOK * FFK_PAD * 2);
    __hip_bfloat16* m_b    = (__hip_bfloat16*)alloc((size_t)512 * MERGED * 2);
    __hip_bfloat16* patch_t= (__hip_bfloat16*)alloc((size_t)DMODEL * PATCHK_PAD * 2);
    __hip_bfloat16* qkv_t  = (__hip_bfloat16*)alloc((size_t)3 * DMODEL * DMODEL * 2);
    __hip_bfloat16* proj_t = (__hip_bfloat16*)alloc((size_t)DMODEL * DMODEL * 2);
    __hip_bfloat16* gate_t = (__hip_bfloat16*)alloc((size_t)FF_PAD * DMODEL * 2);
    __hip_bfloat16* up_t   = (__hip_bfloat16*)alloc((size_t)FF_PAD * DMODEL * 2);
    __hip_bfloat16* down_t = (__hip_bfloat16*)alloc((size_t)DMODEL * FFK_PAD * 2);
    __hip_bfloat16* fc1_t  = (__hip_bfloat16*)alloc((size_t)MERGED * MERGED * 2);
    __hip_bfloat16* fc2_t  = (__hip_bfloat16*)alloc((size_t)OUTD * MERGED * 2);

    const dim3 blk(256);
    auto gemm = [&](const __hip_bfloat16* A, const __hip_bfloat16* Bt,
                    const float* bias, const float* res, float* C,
                    int M, int Nreal, int Nc, int Kp) {
        dim3 grid(Nc / 128, M / 128);
        gemm_bf16<<<grid, blk, 0, stream>>>((const ushort_t*)A, (const ushort_t*)Bt,
                                            bias, res, C, M, Nreal, Nc, Kp);
    };
    auto tcvt = [&](const float* in, __hip_bfloat16* o2, int K, int N, int Kp, int Np) {
        dim3 grid((Kp + 31) / 32, (Np + 31) / 32);
        transpose_cvt<<<grid, blk, 0, stream>>>(in, o2, K, N, Kp, Np);
    };

    // one-time (per call) conversions
    cvt_pad<<<(T_TOK * PATCHK_PAD + 255) / 256, blk, 0, stream>>>(
        x, x_b, T_TOK, PATCH_INDIM, PATCHK_PAD);
    tcvt(patch_w, patch_t, PATCH_INDIM, DMODEL, PATCHK_PAD, DMODEL);
    tcvt(fc1_w, fc1_t, MERGED, MERGED, MERGED, MERGED);
    tcvt(fc2_w, fc2_t, MERGED, OUTD, MERGED, OUTD);

    // h = x @ patch_w
    gemm(x_b, patch_t, nullptr, nullptr, h, T_TOK, DMODEL, DMODEL, PATCHK_PAD);

    for (int l = 0; l < DEPTH_L; l++) {
        tcvt(qkv_w + (size_t)l * DMODEL * 3 * DMODEL, qkv_t, DMODEL, 3 * DMODEL,
             DMODEL, 3 * DMODEL);
        tcvt(proj_w + (size_t)l * DMODEL * DMODEL, proj_t, DMODEL, DMODEL,
             DMODEL, DMODEL);
        tcvt(gate_w + (size_t)l * DMODEL * FFDIM, gate_t, DMODEL, FFDIM,
             DMODEL, FF_PAD);
        tcvt(up_w + (size_t)l * DMODEL * FFDIM, up_t, DMODEL, FFDIM,
             DMODEL, FF_PAD);
        tcvt(down_w + (size_t)l * FFDIM * DMODEL, down_t, FFDIM, DMODEL,
             FFK_PAD, DMODEL);

        rmsnorm_kernel<<<T_TOK, blk, 0, stream>>>(h, norm1_s + l * DMODEL, n_b, DMODEL);
        gemm(n_b, qkv_t, qkv_b + l * 3 * DMODEL, nullptr, qkvf,
             T_TOK, 3 * DMODEL, 3 * DMODEL, DMODEL);
        rope_kernel<<<(T_TOK * NHEAD * HALFD + 255) / 256, blk, 0, stream>>>(qkvf, rpe);
        attn_kernel<<<dim3(NWIN, NHEAD), blk, 0, stream>>>(qkvf, o_b);
        gemm(o_b, proj_t, proj_b + l * DMODEL, h, h, T_TOK, DMODEL, DMODEL, DMODEL);

        rmsnorm_kernel<<<T_TOK, blk, 0, stream>>>(h, norm2_s + l * DMODEL, n_b, DMODEL);
        gemm(n_b, gate_t, gate_b + l * FFDIM, nullptr, gf,
             T_TOK, FFDIM, FF_PAD, DMODEL);
        gemm(n_b, up_t, up_b + l * FFDIM, nullptr, uf,
             T_TOK, FFDIM, FF_PAD, DMODEL);
        silumul_kernel<<<(T_TOK * FFK_PAD + 255) / 256, blk, 0, stream>>>(gf, uf, g_b);
        gemm(g_b, down_t, down_b + l * DMODEL, h, h, T_TOK, DMODEL, DMODEL, FFK_PAD);
    }

    rmsnorm_kernel<<<T_TOK, blk, 0, stream>>>(h, lnq_s, n_b, DMODEL);
    // n_b viewed as [512, 5120]
    gemm(n_b, fc1_t, fc1_b, nullptr, fc1f, 512, MERGED, MERGED, MERGED);
    gelu_kernel<<<(512 * MERGED + 255) / 256, blk, 0, stream>>>(fc1f, m_b, 512 * MERGED);
    gemm(m_b, fc2_t, fc2_b, nullptr, out, 512, OUTD, OUTD, MERGED);
}